// Round 1
// baseline (887.287 us; speedup 1.0000x reference)
//
#include <hip/hip_runtime.h>
#include <hip/hip_bf16.h>
#include <cstdint>
#include <cstddef>

#define N_TOK 8192
#define DIM   2048
#define HID   2048
#define NE    8

typedef _Float16 half8 __attribute__((ext_vector_type(8)));
typedef _Float16 half4v __attribute__((ext_vector_type(4)));
typedef float    floatx4 __attribute__((ext_vector_type(4)));

__device__ inline void gload_lds16(const void* g, void* l) {
    __builtin_amdgcn_global_load_lds(
        (const __attribute__((address_space(1))) unsigned int*)g,
        (__attribute__((address_space(3))) unsigned int*)l, 16, 0, 0);
}

// ---------------- x fp32 -> fp16, plus zero routing counters ----------------
__global__ __launch_bounds__(256) void k_conv_x(const float* __restrict__ in,
                                                _Float16* __restrict__ out,
                                                long n, int* counts) {
    if (blockIdx.x == 0 && threadIdx.x < 16) counts[threadIdx.x] = 0; // counts+fill
    long i = (long)blockIdx.x * blockDim.x + threadIdx.x;
    long stride = (long)gridDim.x * blockDim.x;
    for (long j = i * 4; j < n; j += stride * 4) {
        float4 v = *(const float4*)(in + j);
        half4v h;
        h[0] = (_Float16)v.x; h[1] = (_Float16)v.y;
        h[2] = (_Float16)v.z; h[3] = (_Float16)v.w;
        *(half4v*)(out + j) = h;
    }
}

// ---------------- W [E][R][C] fp32 -> [E][C][R] fp16 ----------------
__global__ __launch_bounds__(256) void k_transpose_f32_f16(const float* __restrict__ in,
                                                           _Float16* __restrict__ out) {
    __shared__ float tile[64][65];
    int e  = blockIdx.z;
    int r0 = blockIdx.y * 64;
    int c0 = blockIdx.x * 64;
    int tc = threadIdx.x & 63, tr = threadIdx.x >> 6; // tr 0..3
    const float* ip = in + ((size_t)e * 2048 + r0) * 2048 + c0;
#pragma unroll
    for (int i = 0; i < 16; i++)
        tile[tr + i * 4][tc] = ip[(size_t)(tr + i * 4) * 2048 + tc];
    __syncthreads();
    _Float16* op = out + ((size_t)e * 2048 + c0) * 2048 + r0;
#pragma unroll
    for (int i = 0; i < 16; i++) {
        int cc = tr + i * 4;
        op[(size_t)cc * 2048 + tc] = (_Float16)tile[tc][cc];
    }
}

// ---------------- gate: logits (fp64 accum), top-2, softmax ----------------
__global__ __launch_bounds__(256) void k_gate(const float* __restrict__ x,
                                              const float* __restrict__ Wg,
                                              const float* __restrict__ bg,
                                              int* __restrict__ te, float* __restrict__ tw,
                                              int* __restrict__ counts) {
    __shared__ float wgs[DIM * NE]; // 64 KB
    for (int i = threadIdx.x; i < DIM * NE / 4; i += 256)
        ((float4*)wgs)[i] = ((const float4*)Wg)[i];
    __syncthreads();
    int wave = threadIdx.x >> 6, lane = threadIdx.x & 63;
#pragma unroll 1
    for (int it = 0; it < 8; ++it) {
        int t = blockIdx.x * 32 + wave * 8 + it;
        double acc[NE];
#pragma unroll
        for (int e = 0; e < NE; e++) acc[e] = 0.0;
        const float* xr = x + (size_t)t * DIM;
#pragma unroll
        for (int i = 0; i < 8; i++) {
            int d0 = i * 256 + lane * 4;
            float4 xv = *(const float4*)(xr + d0);
            float xs[4] = {xv.x, xv.y, xv.z, xv.w};
#pragma unroll
            for (int j = 0; j < 4; j++) {
                const float* wr = &wgs[(d0 + j) * NE];
#pragma unroll
                for (int e = 0; e < NE; e++) acc[e] += (double)xs[j] * (double)wr[e];
            }
        }
#pragma unroll
        for (int e = 0; e < NE; e++) {
            double v = acc[e];
            v += __shfl_xor(v, 32, 64); v += __shfl_xor(v, 16, 64);
            v += __shfl_xor(v, 8, 64);  v += __shfl_xor(v, 4, 64);
            v += __shfl_xor(v, 2, 64);  v += __shfl_xor(v, 1, 64);
            acc[e] = v;
        }
        if (lane == 0) {
            double best0 = -1e300, best1 = -1e300; int i0 = 0, i1 = 0;
#pragma unroll
            for (int e = 0; e < NE; e++) {
                double l = acc[e] + (double)bg[e];
                if (l > best0) { best1 = best0; i1 = i0; best0 = l; i0 = e; }
                else if (l > best1) { best1 = l; i1 = e; }
            }
            float d  = expf((float)(best1 - best0));
            float w0 = 1.f / (1.f + d), w1 = d / (1.f + d);
            te[2 * t] = i0; te[2 * t + 1] = i1;
            tw[2 * t] = w0; tw[2 * t + 1] = w1;
            atomicAdd(&counts[i0], 1);
            atomicAdd(&counts[i1], 1);
        }
    }
}

// ---------------- tiny scan ----------------
__global__ void k_scan(const int* __restrict__ counts, int* __restrict__ offs,
                       int* __restrict__ fill) {
    if (threadIdx.x == 0 && blockIdx.x == 0) {
        int s = 0;
        for (int e = 0; e < NE; e++) { offs[e] = s; s += counts[e]; fill[e] = 0; }
        offs[NE] = s;
    }
}

// ---------------- scatter tokens to expert lists ----------------
__global__ __launch_bounds__(256) void k_scatter(const int* __restrict__ te,
                                                 const float* __restrict__ tw,
                                                 const int* __restrict__ offs,
                                                 int* __restrict__ fill,
                                                 int* __restrict__ ltok,
                                                 float* __restrict__ lw,
                                                 int* __restrict__ tslot) {
    int t = blockIdx.x * blockDim.x + threadIdx.x;
    if (t >= N_TOK) return;
#pragma unroll
    for (int k = 0; k < 2; k++) {
        int e = te[2 * t + k];
        int p = atomicAdd(&fill[e], 1);
        int idx = offs[e] + p;
        ltok[idx] = t; lw[idx] = tw[2 * t + k]; tslot[2 * t + k] = idx;
    }
}

// ---------------- GEMM layer 1: h = relu(x @ W1 + b1), gathered rows ----------------
__global__ __launch_bounds__(256) void k_gemm1(const _Float16* __restrict__ xh,
                                               const _Float16* __restrict__ w1t,
                                               const float* __restrict__ b1,
                                               const int* __restrict__ counts,
                                               const int* __restrict__ offs,
                                               const int* __restrict__ ltok,
                                               _Float16* __restrict__ hbuf) {
    int e = blockIdx.z;
    int cnt = counts[e];
    int m0 = blockIdx.y * 128;
    if (m0 >= cnt) return;
    int n0 = blockIdx.x * 128;
    int base = offs[e];

    __shared__ _Float16 As[128 * 64];
    __shared__ _Float16 Bs[128 * 64];

    int tid = threadIdx.x;
    int lane = tid & 63;
    int wid = tid >> 6;
    int wm = wid >> 1, wn = wid & 1;

    int srow = tid >> 3;          // 0..31
    int scol = (tid & 7) * 8;     // fp16 offset in K
    const _Float16* aPtr[4];
    const _Float16* bPtr[4];
#pragma unroll
    for (int i = 0; i < 4; i++) {
        int r = srow + i * 32;
        int rr = m0 + r; if (rr > cnt - 1) rr = cnt - 1;
        int tok = ltok[base + rr];
        aPtr[i] = xh + (size_t)tok * DIM + scol;
        bPtr[i] = w1t + ((size_t)e * HID + n0 + r) * DIM + scol;
    }
    floatx4 acc[4][4];
#pragma unroll
    for (int m = 0; m < 4; m++)
#pragma unroll
        for (int n = 0; n < 4; n++) acc[m][n] = (floatx4){0.f, 0.f, 0.f, 0.f};

    int aoff = lane & 15;
    int koff = (lane >> 4) * 8;

    for (int kt = 0; kt < DIM / 64; ++kt) {
#pragma unroll
        for (int i = 0; i < 4; i++) gload_lds16(aPtr[i] + kt * 64, &As[tid * 8 + i * 2048]);
#pragma unroll
        for (int i = 0; i < 4; i++) gload_lds16(bPtr[i] + kt * 64, &Bs[tid * 8 + i * 2048]);
        __syncthreads();
#pragma unroll
        for (int kk = 0; kk < 2; kk++) {
            half8 af[4], bf[4];
#pragma unroll
            for (int m = 0; m < 4; m++)
                af[m] = *(const half8*)&As[(wm * 64 + m * 16 + aoff) * 64 + kk * 32 + koff];
#pragma unroll
            for (int n = 0; n < 4; n++)
                bf[n] = *(const half8*)&Bs[(wn * 64 + n * 16 + aoff) * 64 + kk * 32 + koff];
#pragma unroll
            for (int m = 0; m < 4; m++)
#pragma unroll
                for (int n = 0; n < 4; n++)
                    acc[m][n] = __builtin_amdgcn_mfma_f32_16x16x32_f16(af[m], bf[n], acc[m][n], 0, 0, 0);
        }
        __syncthreads();
    }

    int rbase = (lane >> 4) * 4;
    int cbase = lane & 15;
#pragma unroll
    for (int n = 0; n < 4; n++) {
        int col = n0 + wn * 64 + n * 16 + cbase;
        float bv = b1[e * HID + col];
#pragma unroll
        for (int m = 0; m < 4; m++) {
            int row0 = m0 + wm * 64 + m * 16 + rbase;
#pragma unroll
            for (int r = 0; r < 4; r++) {
                int row = row0 + r;
                if (row < cnt) {
                    float v = acc[m][n][r] + bv;
                    v = v > 0.f ? v : 0.f;
                    hbuf[(size_t)(base + row) * HID + col] = (_Float16)v;
                }
            }
        }
    }
}

// ---------------- GEMM layer 2: y = (h @ W2 + b2) * gate_w ----------------
__global__ __launch_bounds__(256) void k_gemm2(const _Float16* __restrict__ hbuf,
                                               const _Float16* __restrict__ w2t,
                                               const float* __restrict__ b2,
                                               const int* __restrict__ counts,
                                               const int* __restrict__ offs,
                                               const float* __restrict__ lw,
                                               _Float16* __restrict__ ybuf) {
    int e = blockIdx.z;
    int cnt = counts[e];
    int m0 = blockIdx.y * 128;
    if (m0 >= cnt) return;
    int n0 = blockIdx.x * 128;
    int base = offs[e];

    __shared__ _Float16 As[128 * 64];
    __shared__ _Float16 Bs[128 * 64];

    int tid = threadIdx.x;
    int lane = tid & 63;
    int wid = tid >> 6;
    int wm = wid >> 1, wn = wid & 1;

    int srow = tid >> 3;
    int scol = (tid & 7) * 8;
    const _Float16* aPtr[4];
    const _Float16* bPtr[4];
#pragma unroll
    for (int i = 0; i < 4; i++) {
        int r = srow + i * 32;
        int rr = m0 + r; if (rr > cnt - 1) rr = cnt - 1;
        aPtr[i] = hbuf + (size_t)(base + rr) * HID + scol;
        bPtr[i] = w2t + ((size_t)e * HID + n0 + r) * HID + scol;
    }
    floatx4 acc[4][4];
#pragma unroll
    for (int m = 0; m < 4; m++)
#pragma unroll
        for (int n = 0; n < 4; n++) acc[m][n] = (floatx4){0.f, 0.f, 0.f, 0.f};

    int aoff = lane & 15;
    int koff = (lane >> 4) * 8;

    for (int kt = 0; kt < HID / 64; ++kt) {
#pragma unroll
        for (int i = 0; i < 4; i++) gload_lds16(aPtr[i] + kt * 64, &As[tid * 8 + i * 2048]);
#pragma unroll
        for (int i = 0; i < 4; i++) gload_lds16(bPtr[i] + kt * 64, &Bs[tid * 8 + i * 2048]);
        __syncthreads();
#pragma unroll
        for (int kk = 0; kk < 2; kk++) {
            half8 af[4], bf[4];
#pragma unroll
            for (int m = 0; m < 4; m++)
                af[m] = *(const half8*)&As[(wm * 64 + m * 16 + aoff) * 64 + kk * 32 + koff];
#pragma unroll
            for (int n = 0; n < 4; n++)
                bf[n] = *(const half8*)&Bs[(wn * 64 + n * 16 + aoff) * 64 + kk * 32 + koff];
#pragma unroll
            for (int m = 0; m < 4; m++)
#pragma unroll
                for (int n = 0; n < 4; n++)
                    acc[m][n] = __builtin_amdgcn_mfma_f32_16x16x32_f16(af[m], bf[n], acc[m][n], 0, 0, 0);
        }
        __syncthreads();
    }

    int rbase = (lane >> 4) * 4;
    int cbase = lane & 15;
#pragma unroll
    for (int n = 0; n < 4; n++) {
        int col = n0 + wn * 64 + n * 16 + cbase;
        float bv = b2[e * HID + col];
#pragma unroll
        for (int m = 0; m < 4; m++) {
            int row0 = m0 + wm * 64 + m * 16 + rbase;
#pragma unroll
            for (int r = 0; r < 4; r++) {
                int row = row0 + r;
                if (row < cnt) {
                    float w = lw[base + row];
                    float v = (acc[m][n][r] + bv) * w;
                    ybuf[(size_t)(base + row) * HID + col] = (_Float16)v;
                }
            }
        }
    }
}

// ---------------- combine the two weighted expert rows per token ----------------
__global__ __launch_bounds__(256) void k_combine(const _Float16* __restrict__ yb,
                                                 const int* __restrict__ tslot,
                                                 float* __restrict__ out) {
    int t = blockIdx.x;
    int s0 = tslot[2 * t], s1 = tslot[2 * t + 1];
    int c = threadIdx.x * 8;
    half8 y0 = *(const half8*)&yb[(size_t)s0 * HID + c];
    half8 y1 = *(const half8*)&yb[(size_t)s1 * HID + c];
    float* op = out + (size_t)t * HID + c;
    float4 o;
    o.x = (float)y0[0] + (float)y1[0];
    o.y = (float)y0[1] + (float)y1[1];
    o.z = (float)y0[2] + (float)y1[2];
    o.w = (float)y0[3] + (float)y1[3];
    *(float4*)(op) = o;
    o.x = (float)y0[4] + (float)y1[4];
    o.y = (float)y0[5] + (float)y1[5];
    o.z = (float)y0[6] + (float)y1[6];
    o.w = (float)y0[7] + (float)y1[7];
    *(float4*)(op + 4) = o;
}

extern "C" void kernel_launch(void* const* d_in, const int* in_sizes, int n_in,
                              void* d_out, int out_size, void* d_ws, size_t ws_size,
                              hipStream_t stream) {
    const float* x  = (const float*)d_in[0];
    const float* Wg = (const float*)d_in[1];
    const float* bg = (const float*)d_in[2];
    const float* W1 = (const float*)d_in[3];
    const float* b1 = (const float*)d_in[4];
    const float* W2 = (const float*)d_in[5];
    const float* b2 = (const float*)d_in[6];
    float* out = (float*)d_out;

    char* ws = (char*)d_ws;
    _Float16* xh  = (_Float16*)(ws);                       // 33,554,432 B
    _Float16* w1t = (_Float16*)(ws + 33554432ULL);         // 67,108,864 B
    _Float16* w2t = (_Float16*)(ws + 100663296ULL);        // 67,108,864 B
    _Float16* hb  = (_Float16*)(ws + 167772160ULL);        // 67,108,864 B
    _Float16* yb  = (_Float16*)(ws + 234881024ULL);        // 67,108,864 B
    char* rt = ws + 301989888ULL;
    int*   counts = (int*)(rt);             // 8 ints (+fill 8 ints at +32)
    int*   fill   = (int*)(rt + 32);
    int*   offs   = (int*)(rt + 64);        // 9 ints
    int*   te     = (int*)(rt + 128);
    float* tw     = (float*)(rt + 128 + 65536);
    int*   ltok   = (int*)(rt + 128 + 131072);
    float* lw     = (float*)(rt + 128 + 196608);
    int*   tslot  = (int*)(rt + 128 + 262144);

    k_conv_x<<<2048, 256, 0, stream>>>(x, xh, (long)N_TOK * DIM, counts);
    k_transpose_f32_f16<<<dim3(32, 32, 8), 256, 0, stream>>>(W1, w1t);
    k_transpose_f32_f16<<<dim3(32, 32, 8), 256, 0, stream>>>(W2, w2t);
    k_gate<<<256, 256, 0, stream>>>(x, Wg, bg, te, tw, counts);
    k_scan<<<1, 64, 0, stream>>>(counts, offs, fill);
    k_scatter<<<32, 256, 0, stream>>>(te, tw, offs, fill, ltok, lw, tslot);
    k_gemm1<<<dim3(16, 64, 8), 256, 0, stream>>>(xh, w1t, b1, counts, offs, ltok, hb);
    k_gemm2<<<dim3(16, 64, 8), 256, 0, stream>>>(hb, w2t, b2, counts, offs, lw, yb);
    k_combine<<<8192, 256, 0, stream>>>(yb, tslot, out);
}

// Round 2
// 850.383 us; speedup vs baseline: 1.0434x; 1.0434x over previous
//
#include <hip/hip_runtime.h>
#include <hip/hip_bf16.h>
#include <cstdint>
#include <cstddef>

#define N_TOK 8192
#define DIM   2048
#define HID   2048
#define NE    8

typedef _Float16 half8  __attribute__((ext_vector_type(8)));
typedef _Float16 half4v __attribute__((ext_vector_type(4)));
typedef float    floatx4 __attribute__((ext_vector_type(4)));

__device__ inline void gload_lds16(const void* g, void* l) {
    __builtin_amdgcn_global_load_lds(
        (const __attribute__((address_space(1))) unsigned int*)g,
        (__attribute__((address_space(3))) unsigned int*)l, 16, 0, 0);
}

// ---------------- W [E][R][C] fp32 -> [E][C][R] fp16 ----------------
__global__ __launch_bounds__(256) void k_transpose_f32_f16(const float* __restrict__ in,
                                                           _Float16* __restrict__ out) {
    __shared__ float tile[64][65];
    int e  = blockIdx.z;
    int r0 = blockIdx.y * 64;
    int c0 = blockIdx.x * 64;
    int tc = threadIdx.x & 63, tr = threadIdx.x >> 6; // tr 0..3
    const float* ip = in + ((size_t)e * 2048 + r0) * 2048 + c0;
#pragma unroll
    for (int i = 0; i < 16; i++)
        tile[tr + i * 4][tc] = ip[(size_t)(tr + i * 4) * 2048 + tc];
    __syncthreads();
    _Float16* op = out + ((size_t)e * 2048 + c0) * 2048 + r0;
#pragma unroll
    for (int i = 0; i < 16; i++) {
        int cc = tr + i * 4;
        op[(size_t)cc * 2048 + tc] = (_Float16)tile[tc][cc];
    }
}

// ---------------- gate: logits (fp64 accum), top-2, softmax; fuses x->fp16 ----------------
__global__ __launch_bounds__(256) void k_gate(const float* __restrict__ x,
                                              const float* __restrict__ Wg,
                                              const float* __restrict__ bg,
                                              _Float16* __restrict__ xh,
                                              int* __restrict__ te, float* __restrict__ tw,
                                              int* __restrict__ counts) {
    __shared__ float wgs[NE * DIM]; // 64 KB, transposed [e][d]
    for (int i = threadIdx.x; i < NE * DIM; i += 256) {
        float v = Wg[i];                       // Wg[d][e]: d=i>>3, e=i&7
        wgs[(i & 7) * DIM + (i >> 3)] = v;
    }
    __syncthreads();
    int wv = threadIdx.x >> 6, l = threadIdx.x & 63;
#pragma unroll 1
    for (int it = 0; it < 8; ++it) {
        int t = blockIdx.x * 32 + wv * 8 + it;
        const float* xr = x + (size_t)t * DIM;
        double acc[NE] = {0, 0, 0, 0, 0, 0, 0, 0};
#pragma unroll
        for (int i = 0; i < 8; i++) {
            int d0 = i * 256 + l * 4;
            float4 xv = *(const float4*)(xr + d0);
            half4v hv;
            hv[0] = (_Float16)xv.x; hv[1] = (_Float16)xv.y;
            hv[2] = (_Float16)xv.z; hv[3] = (_Float16)xv.w;
            *(half4v*)(xh + (size_t)t * DIM + d0) = hv;
#pragma unroll
            for (int e = 0; e < NE; e++) {
                float4 w4 = *(const float4*)(wgs + e * DIM + d0);
                acc[e] += (double)xv.x * w4.x + (double)xv.y * w4.y +
                          (double)xv.z * w4.z + (double)xv.w * w4.w;
            }
        }
#pragma unroll
        for (int e = 0; e < NE; e++) {
            double v = acc[e];
            v += __shfl_xor(v, 32, 64); v += __shfl_xor(v, 16, 64);
            v += __shfl_xor(v, 8, 64);  v += __shfl_xor(v, 4, 64);
            v += __shfl_xor(v, 2, 64);  v += __shfl_xor(v, 1, 64);
            acc[e] = v;
        }
        if (l == 0) {
            double best0 = -1e300, best1 = -1e300; int i0 = 0, i1 = 0;
#pragma unroll
            for (int e = 0; e < NE; e++) {
                double lg = acc[e] + (double)bg[e];
                if (lg > best0) { best1 = best0; i1 = i0; best0 = lg; i0 = e; }
                else if (lg > best1) { best1 = lg; i1 = e; }
            }
            float d  = expf((float)(best1 - best0));
            float w0 = 1.f / (1.f + d), w1 = d / (1.f + d);
            te[2 * t] = i0; te[2 * t + 1] = i1;
            tw[2 * t] = w0; tw[2 * t + 1] = w1;
            atomicAdd(&counts[i0], 1);
            atomicAdd(&counts[i1], 1);
        }
    }
}

// ---------------- tiny scan ----------------
__global__ void k_scan(const int* __restrict__ counts, int* __restrict__ offs,
                       int* __restrict__ fill) {
    if (threadIdx.x == 0 && blockIdx.x == 0) {
        int s = 0;
        for (int e = 0; e < NE; e++) { offs[e] = s; s += counts[e]; fill[e] = 0; }
        offs[NE] = s;
    }
}

// ---------------- scatter tokens to expert lists ----------------
__global__ __launch_bounds__(256) void k_scatter(const int* __restrict__ te,
                                                 const float* __restrict__ tw,
                                                 const int* __restrict__ offs,
                                                 int* __restrict__ fill,
                                                 int* __restrict__ ltok,
                                                 float* __restrict__ lw,
                                                 int* __restrict__ tslot) {
    int t = blockIdx.x * blockDim.x + threadIdx.x;
    if (t >= N_TOK) return;
#pragma unroll
    for (int k = 0; k < 2; k++) {
        int e = te[2 * t + k];
        int p = atomicAdd(&fill[e], 1);
        int idx = offs[e] + p;
        ltok[idx] = t; lw[idx] = tw[2 * t + k]; tslot[2 * t + k] = idx;
    }
}

// ================= deep-pipelined GEMM (BM=256, BN=128, BK=64, ring-3) =================
// 512 threads = 8 waves, wave grid 4m x 2n, wave tile 64x64 (4x4 frags of 16x16).
// LDS: As 3x[256][64] fp16 (96KB) + Bs 3x[128][64] fp16 (48KB) = 144KB.
// XOR swizzle: phys_chunk = logical_chunk ^ (row & 7)  (chunk = 16B of the 128B row).
// Stage lead = 2 K-tiles into buffer (t+2)%3 (held tile t-1, fully consumed).
// vmcnt(6) at tile end => tile t+1 landed, t+2's 6 loads stay in flight.

template<bool STG, int VMW>
__device__ __forceinline__ void tile_body(
    int t, int tid, int awr0, int bwr, int cbo0, int cbo1,
    int& cbuf, int& sbuf,
    _Float16* As, _Float16* Bs,
    const _Float16* aSrc0, const _Float16* aSrc1,
    const _Float16* aSrc2, const _Float16* aSrc3,
    const _Float16* bSrc0, const _Float16* bSrc1,
    floatx4 (&acc)[4][4]) {

    const _Float16* Ab = As + cbuf * (256 * 64);
    const _Float16* Bb = Bs + cbuf * (128 * 64);
    half8 af[2][2], bf[4][2];

    // ---- phase 0: ds-reads (A fm 0-1, all B), stage 3 half-tiles of t+2 ----
#pragma unroll
    for (int i = 0; i < 2; i++) {
        af[i][0] = *(const half8*)(Ab + (awr0 + i * 16) * 64 + cbo0);
        af[i][1] = *(const half8*)(Ab + (awr0 + i * 16) * 64 + cbo1);
    }
#pragma unroll
    for (int n = 0; n < 4; n++) {
        bf[n][0] = *(const half8*)(Bb + (bwr + n * 16) * 64 + cbo0);
        bf[n][1] = *(const half8*)(Bb + (bwr + n * 16) * 64 + cbo1);
    }
    if constexpr (STG) {
        _Float16* Ad = As + sbuf * (256 * 64);
        _Float16* Bd = Bs + sbuf * (128 * 64);
        gload_lds16(aSrc0 + (size_t)(t + 2) * 64, Ad + tid * 8);
        gload_lds16(aSrc1 + (size_t)(t + 2) * 64, Ad + tid * 8 + 4096);
        gload_lds16(bSrc0 + (size_t)(t + 2) * 64, Bd + tid * 8);
    }
    __builtin_amdgcn_s_barrier();
    asm volatile("s_waitcnt lgkmcnt(0)" ::: "memory");
    __builtin_amdgcn_sched_barrier(0);
    __builtin_amdgcn_s_setprio(1);
#pragma unroll
    for (int n = 0; n < 4; n++)
#pragma unroll
        for (int i = 0; i < 2; i++) {
            acc[i][n] = __builtin_amdgcn_mfma_f32_16x16x32_f16(af[i][0], bf[n][0], acc[i][n], 0, 0, 0);
            acc[i][n] = __builtin_amdgcn_mfma_f32_16x16x32_f16(af[i][1], bf[n][1], acc[i][n], 0, 0, 0);
        }
    __builtin_amdgcn_s_setprio(0);
    __builtin_amdgcn_s_barrier();

    // ---- phase 1: ds-reads (A fm 2-3), stage remaining 3 half-tiles ----
#pragma unroll
    for (int i = 0; i < 2; i++) {
        af[i][0] = *(const half8*)(Ab + (awr0 + (i + 2) * 16) * 64 + cbo0);
        af[i][1] = *(const half8*)(Ab + (awr0 + (i + 2) * 16) * 64 + cbo1);
    }
    if constexpr (STG) {
        _Float16* Ad = As + sbuf * (256 * 64);
        _Float16* Bd = Bs + sbuf * (128 * 64);
        gload_lds16(aSrc2 + (size_t)(t + 2) * 64, Ad + tid * 8 + 8192);
        gload_lds16(aSrc3 + (size_t)(t + 2) * 64, Ad + tid * 8 + 12288);
        gload_lds16(bSrc1 + (size_t)(t + 2) * 64, Bd + tid * 8 + 4096);
    }
    __builtin_amdgcn_s_barrier();
    asm volatile("s_waitcnt lgkmcnt(0)" ::: "memory");
    __builtin_amdgcn_sched_barrier(0);
    __builtin_amdgcn_s_setprio(1);
#pragma unroll
    for (int n = 0; n < 4; n++)
#pragma unroll
        for (int i = 0; i < 2; i++) {
            acc[2 + i][n] = __builtin_amdgcn_mfma_f32_16x16x32_f16(af[i][0], bf[n][0], acc[2 + i][n], 0, 0, 0);
            acc[2 + i][n] = __builtin_amdgcn_mfma_f32_16x16x32_f16(af[i][1], bf[n][1], acc[2 + i][n], 0, 0, 0);
        }
    __builtin_amdgcn_s_setprio(0);
    if constexpr (VMW == 6) asm volatile("s_waitcnt vmcnt(6)" ::: "memory");
    else if constexpr (VMW == 0) asm volatile("s_waitcnt vmcnt(0)" ::: "memory");
    __builtin_amdgcn_s_barrier();
    cbuf = (cbuf == 2) ? 0 : cbuf + 1;
    sbuf = (sbuf == 2) ? 0 : sbuf + 1;
}

template<int LAYER>
__global__ __launch_bounds__(512, 2) void k_gemm(const _Float16* __restrict__ Ain,
                                                 const _Float16* __restrict__ Bt,
                                                 const float* __restrict__ bias,
                                                 const int* __restrict__ counts,
                                                 const int* __restrict__ offs,
                                                 const int* __restrict__ ltok,
                                                 const float* __restrict__ lw,
                                                 _Float16* __restrict__ Cout) {
    __shared__ _Float16 As[3 * 256 * 64];
    __shared__ _Float16 Bs[3 * 128 * 64];

    // XCD-chunked remap: logical L = (hw%8)*512 + hw/8 so 512 logical-consecutive
    // blocks (sharing A/B panels) stay on one XCD. 4096 % 8 == 0 -> bijective.
    int L = (blockIdx.x & 7) * 512 + (blockIdx.x >> 3);
    int e   = L >> 9;
    int rem = L & 511;
    int m0 = (rem >> 4) * 256;
    int n0 = (rem & 15) * 128;

    int cnt = counts[e];
    if (m0 >= cnt) return;
    int base = offs[e];

    int tid = threadIdx.x;
    int l = tid & 63, wid = tid >> 6;
    int wm = wid >> 1, wn = wid & 1;
    int lr = l & 15, lk = l >> 4;
    int cbo0 = ((lk) ^ (l & 7)) * 8;       // kk=0 chunk, in fp16 elems
    int cbo1 = ((4 + lk) ^ (l & 7)) * 8;   // kk=1 chunk
    int awr0 = wm * 64 + lr;
    int bwr  = wn * 64 + lr;

    // staging source addresses (pre-swizzled global chunk)
    int srow  = tid >> 3;                              // 0..63
    size_t koff = (size_t)(((tid & 7) ^ (srow & 7)) * 8); // fp16 elems
    const _Float16* aSrc[4];
#pragma unroll
    for (int j = 0; j < 4; j++) {
        int r = m0 + srow + j * 64; if (r > cnt - 1) r = cnt - 1;
        if constexpr (LAYER == 1) {
            int tok = ltok[base + r];
            aSrc[j] = Ain + (size_t)tok * DIM + koff;
        } else {
            aSrc[j] = Ain + (size_t)(base + r) * HID + koff;
        }
    }
    const _Float16* bSrc[2];
#pragma unroll
    for (int j = 0; j < 2; j++)
        bSrc[j] = Bt + ((size_t)e * 2048 + n0 + srow + j * 64) * 2048 + koff;

    floatx4 acc[4][4];
#pragma unroll
    for (int m = 0; m < 4; m++)
#pragma unroll
        for (int n = 0; n < 4; n++) acc[m][n] = (floatx4){0.f, 0.f, 0.f, 0.f};

    // prologue: stage tiles 0,1 (order matters for vmcnt accounting)
#pragma unroll
    for (int T = 0; T < 2; T++) {
        _Float16* Ad = As + T * (256 * 64);
        _Float16* Bd = Bs + T * (128 * 64);
#pragma unroll
        for (int j = 0; j < 4; j++) gload_lds16(aSrc[j] + (size_t)T * 64, Ad + tid * 8 + j * 4096);
#pragma unroll
        for (int j = 0; j < 2; j++) gload_lds16(bSrc[j] + (size_t)T * 64, Bd + tid * 8 + j * 4096);
    }
    asm volatile("s_waitcnt vmcnt(6)" ::: "memory");  // tile0 landed; tile1 in flight
    __builtin_amdgcn_s_barrier();

    int cbuf = 0, sbuf = 2;
    const int NT = DIM / 64;  // 32
#pragma unroll 1
    for (int t = 0; t < NT - 2; ++t)
        tile_body<true, 6>(t, tid, awr0, bwr, cbo0, cbo1, cbuf, sbuf, As, Bs,
                           aSrc[0], aSrc[1], aSrc[2], aSrc[3], bSrc[0], bSrc[1], acc);
    tile_body<false, 0>(NT - 2, tid, awr0, bwr, cbo0, cbo1, cbuf, sbuf, As, Bs,
                        aSrc[0], aSrc[1], aSrc[2], aSrc[3], bSrc[0], bSrc[1], acc);
    tile_body<false, -1>(NT - 1, tid, awr0, bwr, cbo0, cbo1, cbuf, sbuf, As, Bs,
                         aSrc[0], aSrc[1], aSrc[2], aSrc[3], bSrc[0], bSrc[1], acc);

    // epilogue
#pragma unroll
    for (int fm = 0; fm < 4; fm++) {
        int row0 = m0 + wm * 64 + fm * 16 + lk * 4;
#pragma unroll
        for (int fn = 0; fn < 4; fn++) {
            int col = n0 + wn * 64 + fn * 16 + lr;
            float bv = bias[e * 2048 + col];
#pragma unroll
            for (int r = 0; r < 4; r++) {
                int row = row0 + r;
                if (row < cnt) {
                    float v = acc[fm][fn][r] + bv;
                    if constexpr (LAYER == 1) {
                        v = v > 0.f ? v : 0.f;
                        Cout[(size_t)(base + row) * HID + col] = (_Float16)v;
                    } else {
                        v *= lw[base + row];
                        Cout[(size_t)(base + row) * HID + col] = (_Float16)v;
                    }
                }
            }
        }
    }
}

// ---------------- combine the two weighted expert rows per token ----------------
__global__ __launch_bounds__(256) void k_combine(const _Float16* __restrict__ yb,
                                                 const int* __restrict__ tslot,
                                                 float* __restrict__ out) {
    int t = blockIdx.x;
    int s0 = tslot[2 * t], s1 = tslot[2 * t + 1];
    int c = threadIdx.x * 8;
    half8 y0 = *(const half8*)&yb[(size_t)s0 * HID + c];
    half8 y1 = *(const half8*)&yb[(size_t)s1 * HID + c];
    float* op = out + (size_t)t * HID + c;
    float4 o;
    o.x = (float)y0[0] + (float)y1[0];
    o.y = (float)y0[1] + (float)y1[1];
    o.z = (float)y0[2] + (float)y1[2];
    o.w = (float)y0[3] + (float)y1[3];
    *(float4*)(op) = o;
    o.x = (float)y0[4] + (float)y1[4];
    o.y = (float)y0[5] + (float)y1[5];
    o.z = (float)y0[6] + (float)y1[6];
    o.w = (float)y0[7] + (float)y1[7];
    *(float4*)(op + 4) = o;
}

extern "C" void kernel_launch(void* const* d_in, const int* in_sizes, int n_in,
                              void* d_out, int out_size, void* d_ws, size_t ws_size,
                              hipStream_t stream) {
    const float* x  = (const float*)d_in[0];
    const float* Wg = (const float*)d_in[1];
    const float* bg = (const float*)d_in[2];
    const float* W1 = (const float*)d_in[3];
    const float* b1 = (const float*)d_in[4];
    const float* W2 = (const float*)d_in[5];
    const float* b2 = (const float*)d_in[6];
    float* out = (float*)d_out;

    char* ws = (char*)d_ws;
    _Float16* xh  = (_Float16*)(ws);                       // 33,554,432 B
    _Float16* w1t = (_Float16*)(ws + 33554432ULL);         // 67,108,864 B
    _Float16* w2t = (_Float16*)(ws + 100663296ULL);        // 67,108,864 B
    _Float16* hb  = (_Float16*)(ws + 167772160ULL);        // 67,108,864 B
    _Float16* yb  = (_Float16*)(ws + 234881024ULL);        // 67,108,864 B
    char* rt = ws + 301989888ULL;
    int*   counts = (int*)(rt);             // 8 ints
    int*   fill   = (int*)(rt + 32);        // 8 ints
    int*   offs   = (int*)(rt + 64);        // 9 ints
    int*   te     = (int*)(rt + 128);
    float* tw     = (float*)(rt + 128 + 65536);
    int*   ltok   = (int*)(rt + 128 + 131072);
    float* lw     = (float*)(rt + 128 + 196608);
    int*   tslot  = (int*)(rt + 128 + 262144);

    hipMemsetAsync(rt, 0, 64, stream);  // counts + fill
    k_transpose_f32_f16<<<dim3(32, 32, 8), 256, 0, stream>>>(W1, w1t);
    k_transpose_f32_f16<<<dim3(32, 32, 8), 256, 0, stream>>>(W2, w2t);
    k_gate<<<256, 256, 0, stream>>>(x, Wg, bg, xh, te, tw, counts);
    k_scan<<<1, 64, 0, stream>>>(counts, offs, fill);
    k_scatter<<<32, 256, 0, stream>>>(te, tw, offs, fill, ltok, lw, tslot);
    k_gemm<1><<<dim3(4096), 512, 0, stream>>>(xh, w1t, b1, counts, offs, ltok, nullptr, hb);
    k_gemm<2><<<dim3(4096), 512, 0, stream>>>(hb, w2t, b2, counts, offs, ltok, lw, yb);
    k_combine<<<8192, 256, 0, stream>>>(yb, tslot, out);
}